// Round 11
// baseline (177.410 us; speedup 1.0000x reference)
//
#include <hip/hip_runtime.h>

#define N_NODES 40000
#define N_EDGES 640000
#define HD 128
#define N_REL2 474
#define BN_EPS 1e-5f
#define NB_SCAN ((N_NODES + 255) / 256)  // 157 scan blocks

// K1: histogram of edge destinations
__global__ __launch_bounds__(256) void k_hist(
        const int* __restrict__ dst, int* __restrict__ counts) {
    int e = blockIdx.x * 256 + threadIdx.x;
    if (e < N_EDGES) atomicAdd(counts + dst[e], 1);
}

// K2a: per-block sum of 256 counts
__global__ __launch_bounds__(256) void k_scan_part(
        const int* __restrict__ counts, int* __restrict__ bsum) {
    __shared__ int ls[256];
    int t = threadIdx.x;
    int idx = blockIdx.x * 256 + t;
    ls[t] = (idx < N_NODES) ? counts[idx] : 0;
    __syncthreads();
    #pragma unroll
    for (int off = 128; off > 0; off >>= 1) {
        if (t < off) ls[t] += ls[t + off];
        __syncthreads();
    }
    if (t == 0) bsum[blockIdx.x] = ls[0];
}

// K2b: per-block local scan; block offset from replicated top-level scan of bsum
__global__ __launch_bounds__(256) void k_scan_down(
        const int* __restrict__ counts, const int* __restrict__ bsum,
        int* __restrict__ row_off, int* __restrict__ cursor) {
    __shared__ int btop[256];
    __shared__ int ls[256];
    int t = threadIdx.x;
    btop[t] = (t < NB_SCAN) ? bsum[t] : 0;
    __syncthreads();
    #pragma unroll
    for (int off = 1; off < 256; off <<= 1) {
        int tmp = (t >= off) ? btop[t - off] : 0;
        __syncthreads();
        btop[t] += tmp;
        __syncthreads();
    }
    int blockoff = (blockIdx.x == 0) ? 0 : btop[blockIdx.x - 1];
    int idx = blockIdx.x * 256 + t;
    int v = (idx < N_NODES) ? counts[idx] : 0;
    ls[t] = v;
    __syncthreads();
    #pragma unroll
    for (int off = 1; off < 256; off <<= 1) {
        int tmp = (t >= off) ? ls[t - off] : 0;
        __syncthreads();
        ls[t] += tmp;
        __syncthreads();
    }
    int excl = ls[t] - v + blockoff;
    if (idx < N_NODES) {
        row_off[idx] = excl;
        cursor[idx] = excl;
    }
    if (idx == N_NODES) row_off[N_NODES] = N_EDGES;
}

// K3: scatter rel id into CSR order — 4B payload (half the line churn of 8B)
__global__ __launch_bounds__(256) void k_sortrel(
        const int* __restrict__ dst, const int* __restrict__ rel_id,
        int* __restrict__ cursor, int* __restrict__ sorted_rel) {
    int e = blockIdx.x * 256 + threadIdx.x;
    if (e < N_EDGES) {
        int p = atomicAdd(cursor + dst[e], 1);
        sorted_rel[p] = rel_id[e];
    }
}

// K4: RW = rel_emb @ neigh_w  (474 x 128 @ 128 x 128), all f32
__global__ __launch_bounds__(128) void k_rw(
        const float* __restrict__ R, const float* __restrict__ W,
        float* __restrict__ RW) {
    __shared__ float row[HD];
    int r = blockIdx.x, c = threadIdx.x;
    row[c] = R[(size_t)r * HD + c];
    __syncthreads();
    float acc = 0.f;
    #pragma unroll 8
    for (int k = 0; k < HD; ++k) acc += row[k] * W[(size_t)k * HD + c];
    RW[(size_t)r * HD + c] = acc;
}

// K5 (fused, all-f32): one wave per node.
//   - ent row staged once in LDS (coalesced f32 read)
//   - chunk of 16 edges: quad computes one edge's dot (8 float4 R loads vs
//     LDS ent) + 2 quad shuffles; p = exp(dot) (no max needed: |dot| << 88)
//   - acc: per edge one LDS p/r broadcast + one float2 RW load per lane;
//     lp accumulated uniformly (no final reduce)
__global__ __launch_bounds__(256) void k_node_all(
        const float* __restrict__ ent_emb, const float* __restrict__ R,
        const float* __restrict__ RW, const int* __restrict__ row_off,
        const int* __restrict__ sorted_rel, float* __restrict__ h) {
    __shared__ __align__(16) float ent_s[4][HD];
    __shared__ int rel_s[4][16];
    __shared__ float p_s[4][16];
    int wave = threadIdx.x >> 6, lane = threadIdx.x & 63;
    int n = blockIdx.x * 4 + wave;
    if (n >= N_NODES) return;
    float2 e2 = ((const float2*)(ent_emb + (size_t)n * HD))[lane];
    ((float2*)ent_s[wave])[lane] = e2;
    int beg = row_off[n], end = row_off[n + 1];
    int q = lane >> 2, sub = lane & 3;  // q: edge slot, sub: dim group
    float lp = 0.f;
    float2 acc = make_float2(0.f, 0.f);
    const float4* es = (const float4*)ent_s[wave];
    for (int base = beg; base < end; base += 16) {
        int cnt = min(16, end - base);
        if (lane < cnt) rel_s[wave][lane] = sorted_rel[base + lane];
        if (q < cnt) {
            int r = rel_s[wave][q];
            const float4* rr = (const float4*)(R + (size_t)r * HD);
            float d = 0.f;
            #pragma unroll
            for (int k = 0; k < 8; ++k) {
                float4 a = rr[sub * 8 + k];
                float4 b = es[sub * 8 + k];
                d += a.x * b.x + a.y * b.y + a.z * b.z + a.w * b.w;
            }
            d += __shfl_xor(d, 1, 64);
            d += __shfl_xor(d, 2, 64);
            if (sub == 0) p_s[wave][q] = __expf(d);
        }
        #pragma unroll 4
        for (int j = 0; j < cnt; ++j) {
            float p = p_s[wave][j];
            int r = rel_s[wave][j];
            float2 wv = ((const float2*)(RW + (size_t)r * HD))[lane];
            lp += p;
            acc.x += p * wv.x;
            acc.y += p * wv.y;
        }
    }
    float invl = (lp > 0.f) ? 1.f / lp : 0.f;
    ((float2*)(h + (size_t)n * HD))[lane] = make_float2(acc.x * invl, acc.y * invl);
}

// K6: per-column sum / sumsq over rows (block-partial -> global atomics)
__global__ __launch_bounds__(256) void k_stats(
        const float* __restrict__ Hout, float* __restrict__ colsum,
        float* __restrict__ colsumsq) {
    __shared__ float ls[256], lq[256];
    int t = threadIdx.x;
    int c = t & 127, half = t >> 7;
    int rbase = blockIdx.x * 64;
    float sum = 0.f, sq = 0.f;
    #pragma unroll 4
    for (int i = 0; i < 32; ++i) {
        int r = rbase + half + i * 2;
        float v = Hout[(size_t)r * HD + c];
        sum += v;
        sq += v * v;
    }
    ls[t] = sum;
    lq[t] = sq;
    __syncthreads();
    if (t < 128) {
        sum = ls[t] + ls[t + 128];
        sq = lq[t] + lq[t + 128];
        atomicAdd(colsum + c, sum);
        atomicAdd(colsumsq + c, sq);
    }
}

// K7: out = tanh((h - mean) * rstd * gamma + beta), in place; fast tanh via __expf
__global__ __launch_bounds__(256) void k_apply(
        float* __restrict__ Hout, const float* __restrict__ colsum,
        const float* __restrict__ colsumsq, const float* __restrict__ gamma,
        const float* __restrict__ beta) {
    int idx = blockIdx.x * 256 + threadIdx.x;  // float4 index
    if (idx >= N_NODES * HD / 4) return;
    int c0 = (idx * 4) & 127;
    float4 hv4 = ((const float4*)Hout)[idx];
    const float inv = 1.f / (float)N_NODES;
    float hv[4] = {hv4.x, hv4.y, hv4.z, hv4.w};
    float o[4];
    #pragma unroll
    for (int j = 0; j < 4; ++j) {
        int c = c0 + j;
        float mean = colsum[c] * inv;
        float var = colsumsq[c] * inv - mean * mean;
        float rstd = rsqrtf(var + BN_EPS);
        float x = (hv[j] - mean) * rstd * gamma[c] + beta[c];
        o[j] = 1.f - 2.f / (__expf(2.f * x) + 1.f);
    }
    ((float4*)Hout)[idx] = make_float4(o[0], o[1], o[2], o[3]);
}

extern "C" void kernel_launch(void* const* d_in, const int* in_sizes, int n_in,
                              void* d_out, int out_size, void* d_ws, size_t ws_size,
                              hipStream_t stream) {
    const float* ent_emb  = (const float*)d_in[0];
    const float* rel_emb  = (const float*)d_in[1];
    const float* neigh_w  = (const float*)d_in[2];
    const float* bn_gamma = (const float*)d_in[3];
    const float* bn_beta  = (const float*)d_in[4];
    const int*   rel_id   = (const int*)d_in[5];
    const int*   dst      = (const int*)d_in[6];
    float* out = (float*)d_out;

    // workspace layout (4-byte units) — first 40256 words are memset to 0
    int*   counts     = (int*)d_ws;            // [40000]
    float* colsum     = (float*)d_ws + 40000;  // [128]
    float* colsumsq   = (float*)d_ws + 40128;  // [128]
    int*   row_off    = (int*)d_ws + 40256;    // [40001]
    int*   cursor     = (int*)d_ws + 80257;    // [40000]
    int*   sorted_rel = (int*)d_ws + 120257;   // [640000]
    float* RW         = (float*)d_ws + 760257; // [474*128]
    int*   bsum       = (int*)d_ws + 820929;   // [NB_SCAN]

    hipMemsetAsync(d_ws, 0, (size_t)40256 * 4, stream);

    k_hist<<<(N_EDGES + 255) / 256, 256, 0, stream>>>(dst, counts);
    k_scan_part<<<NB_SCAN, 256, 0, stream>>>(counts, bsum);
    k_scan_down<<<NB_SCAN, 256, 0, stream>>>(counts, bsum, row_off, cursor);
    k_sortrel<<<(N_EDGES + 255) / 256, 256, 0, stream>>>(dst, rel_id, cursor, sorted_rel);
    k_rw<<<N_REL2, 128, 0, stream>>>(rel_emb, neigh_w, RW);
    k_node_all<<<N_NODES / 4, 256, 0, stream>>>(ent_emb, rel_emb, RW, row_off, sorted_rel, out);
    k_stats<<<N_NODES / 64, 256, 0, stream>>>(out, colsum, colsumsq);
    k_apply<<<N_NODES * HD / 4 / 256, 256, 0, stream>>>(out, colsum, colsumsq, bn_gamma, bn_beta);
}

// Round 12
// 171.223 us; speedup vs baseline: 1.0361x; 1.0361x over previous
//
#include <hip/hip_runtime.h>

#define N_NODES 40000
#define N_EDGES 640000
#define HD 128
#define N_REL2 474
#define BN_EPS 1e-5f
#define NB_SCAN ((N_NODES + 255) / 256)  // 157 scan blocks

typedef _Float16 half2_t __attribute__((ext_vector_type(2)));

static __device__ __forceinline__ float dot2acc(half2_t a, half2_t b, float c) {
#if __has_builtin(__builtin_amdgcn_fdot2)
    return __builtin_amdgcn_fdot2(a, b, c, false);
#else
    return c + (float)a[0] * (float)b[0] + (float)a[1] * (float)b[1];
#endif
}

// K1: histogram of edge destinations
__global__ __launch_bounds__(256) void k_hist(
        const int* __restrict__ dst, int* __restrict__ counts) {
    int e = blockIdx.x * 256 + threadIdx.x;
    if (e < N_EDGES) atomicAdd(counts + dst[e], 1);
}

// K2a: per-block sum of 256 counts
__global__ __launch_bounds__(256) void k_scan_part(
        const int* __restrict__ counts, int* __restrict__ bsum) {
    __shared__ int ls[256];
    int t = threadIdx.x;
    int idx = blockIdx.x * 256 + t;
    ls[t] = (idx < N_NODES) ? counts[idx] : 0;
    __syncthreads();
    #pragma unroll
    for (int off = 128; off > 0; off >>= 1) {
        if (t < off) ls[t] += ls[t + off];
        __syncthreads();
    }
    if (t == 0) bsum[blockIdx.x] = ls[0];
}

// K2b: per-block local scan; block offset from replicated top scan of bsum.
//      Writes row_off AND overwrites counts with the same value (cursor reuse).
__global__ __launch_bounds__(256) void k_scan_down(
        int* __restrict__ counts, const int* __restrict__ bsum,
        int* __restrict__ row_off) {
    __shared__ int btop[256];
    __shared__ int ls[256];
    int t = threadIdx.x;
    btop[t] = (t < NB_SCAN) ? bsum[t] : 0;
    __syncthreads();
    #pragma unroll
    for (int off = 1; off < 256; off <<= 1) {
        int tmp = (t >= off) ? btop[t - off] : 0;
        __syncthreads();
        btop[t] += tmp;
        __syncthreads();
    }
    int blockoff = (blockIdx.x == 0) ? 0 : btop[blockIdx.x - 1];
    int idx = blockIdx.x * 256 + t;
    int v = (idx < N_NODES) ? counts[idx] : 0;
    ls[t] = v;
    __syncthreads();
    #pragma unroll
    for (int off = 1; off < 256; off <<= 1) {
        int tmp = (t >= off) ? ls[t - off] : 0;
        __syncthreads();
        ls[t] += tmp;
        __syncthreads();
    }
    int excl = ls[t] - v + blockoff;
    if (idx < N_NODES) {
        row_off[idx] = excl;
        counts[idx] = excl;  // counts becomes the scatter cursor
    }
    if (idx == N_NODES) row_off[N_NODES] = N_EDGES;
}

// K3: ent f32 -> fp16 hi|lo rows of 256 halfs ([0:128]=hi, [128:256]=lo)
__global__ __launch_bounds__(256) void k_cvt_ent(
        const float* __restrict__ ent, _Float16* __restrict__ ent_hl) {
    int i = blockIdx.x * 256 + threadIdx.x;  // one 8-dim chunk
    if (i >= N_NODES * HD / 8) return;
    int n = i >> 4, c8 = i & 15;
    float4 a = ((const float4*)ent)[i * 2];
    float4 b = ((const float4*)ent)[i * 2 + 1];
    float v[8] = {a.x, a.y, a.z, a.w, b.x, b.y, b.z, b.w};
    union { _Float16 h[8]; float4 f4; } hi, lo;
    #pragma unroll
    for (int k = 0; k < 8; ++k) {
        _Float16 hh = (_Float16)v[k];
        hi.h[k] = hh;
        lo.h[k] = (_Float16)(v[k] - (float)hh);
    }
    *(float4*)(ent_hl + (size_t)n * 256 + c8 * 8) = hi.f4;
    *(float4*)(ent_hl + (size_t)n * 256 + 128 + c8 * 8) = lo.f4;
}

// K4: RW = rel_emb @ neigh_w (f32) + R -> fp16 hi|lo rows
__global__ __launch_bounds__(128) void k_rw(
        const float* __restrict__ R, const float* __restrict__ W,
        float* __restrict__ RW, _Float16* __restrict__ R_hl) {
    __shared__ float row[HD];
    int r = blockIdx.x, c = threadIdx.x;
    float rv = R[(size_t)r * HD + c];
    row[c] = rv;
    _Float16 hh = (_Float16)rv;
    R_hl[(size_t)r * 256 + c] = hh;
    R_hl[(size_t)r * 256 + 128 + c] = (_Float16)(rv - (float)hh);
    __syncthreads();
    float acc = 0.f;
    #pragma unroll 8
    for (int k = 0; k < HD; ++k) acc += row[k] * W[(size_t)k * HD + c];
    RW[(size_t)r * HD + c] = acc;
}

// K5 (fused dot+exp+pack+CSR-scatter): original edge order, 16 lanes/edge.
//   s = (ahi+alo)·(bhi+blo) via 3 fdot2 terms (lo·lo negligible) — f32-exact.
//   payload 4B: rel(9b) | s-fixed-point(23b, x65536).
__global__ __launch_bounds__(256) void k_edge_all(
        const _Float16* __restrict__ ent_hl, const _Float16* __restrict__ R_hl,
        const int* __restrict__ rel_id, const int* __restrict__ dst,
        int* __restrict__ cursor, unsigned* __restrict__ packed) {
    int t = threadIdx.x;
    int e = blockIdx.x * 16 + (t >> 4);
    int lam = t & 15;
    int r = rel_id[e], d = dst[e];
    const float4* ap = (const float4*)(R_hl + (size_t)r * 256);
    const float4* bp = (const float4*)(ent_hl + (size_t)d * 256);
    float4 ah4 = ap[lam], al4 = ap[lam + 16];
    float4 bh4 = bp[lam], bl4 = bp[lam + 16];
    const half2_t* ah = (const half2_t*)&ah4;
    const half2_t* al = (const half2_t*)&al4;
    const half2_t* bh = (const half2_t*)&bh4;
    const half2_t* bl = (const half2_t*)&bl4;
    float s = 0.f;
    #pragma unroll
    for (int k = 0; k < 4; ++k) {
        s = dot2acc(ah[k], bh[k], s);
        s = dot2acc(ah[k], bl[k], s);
        s = dot2acc(al[k], bh[k], s);
    }
    #pragma unroll
    for (int m = 8; m >= 1; m >>= 1) s += __shfl_xor(s, m, 64);  // 16-group
    if (lam == 0) {
        float sc = fminf(fmaxf(s, -63.9f), 63.9f);
        int si = (int)rintf(sc * 65536.f);          // |si| < 2^22
        unsigned pkt = ((unsigned)r << 23) | ((unsigned)si & 0x7FFFFFu);
        int pos = atomicAdd(cursor + d, 1);
        packed[pos] = pkt;
    }
}

// K6: gather-accumulate (R8-proven). One wave per node; decode packed;
//   lane=(g,c4): g takes edges j%4==g, c4 owns cols [c4*8, c4*8+8).
__global__ __launch_bounds__(256) void k_node_acc(
        const float* __restrict__ RW, const int* __restrict__ row_off,
        const unsigned* __restrict__ packed, float* __restrict__ h) {
    __shared__ unsigned pk_s[4][64];
    int wave = threadIdx.x >> 6, lane = threadIdx.x & 63;
    int n = blockIdx.x * 4 + wave;
    if (n >= N_NODES) return;
    int beg = row_off[n], end = row_off[n + 1];
    int c4 = lane & 15, g = lane >> 4;
    float acc[8] = {};
    float lp = 0.f;
    const float4* RW4 = (const float4*)RW;
    for (int base = beg; base < end; base += 64) {
        int cnt = min(64, end - base);
        if (lane < cnt) pk_s[wave][lane] = packed[base + lane];
        // wave-synchronous LDS (in-order within wave)
        for (int j0 = 0; j0 < cnt; j0 += 4) {
            int eidx = j0 + g;
            if (eidx < cnt) {
                unsigned pkt = pk_s[wave][eidx];
                int r = pkt >> 23;
                float sv = (float)(((int)(pkt << 9)) >> 9) * (1.f / 65536.f);
                float p = __expf(sv);
                const float4* rowp = RW4 + (size_t)r * 32 + c4 * 2;
                float4 w0 = rowp[0], w1 = rowp[1];
                lp += p;
                acc[0] += p * w0.x; acc[1] += p * w0.y;
                acc[2] += p * w0.z; acc[3] += p * w0.w;
                acc[4] += p * w1.x; acc[5] += p * w1.y;
                acc[6] += p * w1.z; acc[7] += p * w1.w;
            }
        }
    }
    #pragma unroll
    for (int m = 16; m <= 32; m <<= 1) {
        lp += __shfl_xor(lp, m, 64);
        #pragma unroll
        for (int k = 0; k < 8; ++k) acc[k] += __shfl_xor(acc[k], m, 64);
    }
    float invl = (lp > 0.f) ? 1.f / lp : 0.f;
    if (g == 0) {
        float4* op = (float4*)(h + (size_t)n * HD + c4 * 8);
        op[0] = make_float4(acc[0] * invl, acc[1] * invl, acc[2] * invl, acc[3] * invl);
        op[1] = make_float4(acc[4] * invl, acc[5] * invl, acc[6] * invl, acc[7] * invl);
    }
}

// K7: per-column sum / sumsq over rows (block-partial -> global atomics)
__global__ __launch_bounds__(256) void k_stats(
        const float* __restrict__ Hout, float* __restrict__ colsum,
        float* __restrict__ colsumsq) {
    __shared__ float ls[256], lq[256];
    int t = threadIdx.x;
    int c = t & 127, half = t >> 7;
    int rbase = blockIdx.x * 64;
    float sum = 0.f, sq = 0.f;
    #pragma unroll 4
    for (int i = 0; i < 32; ++i) {
        int r = rbase + half + i * 2;
        float v = Hout[(size_t)r * HD + c];
        sum += v;
        sq += v * v;
    }
    ls[t] = sum;
    lq[t] = sq;
    __syncthreads();
    if (t < 128) {
        sum = ls[t] + ls[t + 128];
        sq = lq[t] + lq[t + 128];
        atomicAdd(colsum + c, sum);
        atomicAdd(colsumsq + c, sq);
    }
}

// K8: out = tanh((h - mean) * rstd * gamma + beta), in place; fast tanh
__global__ __launch_bounds__(256) void k_apply(
        float* __restrict__ Hout, const float* __restrict__ colsum,
        const float* __restrict__ colsumsq, const float* __restrict__ gamma,
        const float* __restrict__ beta) {
    int idx = blockIdx.x * 256 + threadIdx.x;  // float4 index
    if (idx >= N_NODES * HD / 4) return;
    int c0 = (idx * 4) & 127;
    float4 hv4 = ((const float4*)Hout)[idx];
    const float inv = 1.f / (float)N_NODES;
    float hv[4] = {hv4.x, hv4.y, hv4.z, hv4.w};
    float o[4];
    #pragma unroll
    for (int j = 0; j < 4; ++j) {
        int c = c0 + j;
        float mean = colsum[c] * inv;
        float var = colsumsq[c] * inv - mean * mean;
        float rstd = rsqrtf(var + BN_EPS);
        float x = (hv[j] - mean) * rstd * gamma[c] + beta[c];
        o[j] = 1.f - 2.f / (__expf(2.f * x) + 1.f);
    }
    ((float4*)Hout)[idx] = make_float4(o[0], o[1], o[2], o[3]);
}

extern "C" void kernel_launch(void* const* d_in, const int* in_sizes, int n_in,
                              void* d_out, int out_size, void* d_ws, size_t ws_size,
                              hipStream_t stream) {
    const float* ent_emb  = (const float*)d_in[0];
    const float* rel_emb  = (const float*)d_in[1];
    const float* neigh_w  = (const float*)d_in[2];
    const float* bn_gamma = (const float*)d_in[3];
    const float* bn_beta  = (const float*)d_in[4];
    const int*   rel_id   = (const int*)d_in[5];
    const int*   dst      = (const int*)d_in[6];
    float* out = (float*)d_out;

    // workspace layout (4-byte words) — first 40256 words memset to 0
    int*      counts  = (int*)d_ws;                         // [40000] then cursor
    float*    colsum  = (float*)d_ws + 40000;               // [128]
    float*    colsumsq= (float*)d_ws + 40128;               // [128]
    int*      row_off = (int*)d_ws + 40256;                 // [40001]
    unsigned* packed  = (unsigned*)d_ws + 80257;            // [640000]
    float*    RW      = (float*)d_ws + 720260;              // [474*128] 16B-aligned
    _Float16* R_hl    = (_Float16*)((float*)d_ws + 780932); // [474*256] 16B-aligned
    _Float16* ent_hl  = (_Float16*)((float*)d_ws + 841604); // [40000*256]
    int*      bsum    = (int*)d_ws + 5961604;               // [NB_SCAN]

    hipMemsetAsync(d_ws, 0, (size_t)40256 * 4, stream);

    k_hist<<<(N_EDGES + 255) / 256, 256, 0, stream>>>(dst, counts);
    k_scan_part<<<NB_SCAN, 256, 0, stream>>>(counts, bsum);
    k_scan_down<<<NB_SCAN, 256, 0, stream>>>(counts, bsum, row_off);
    k_cvt_ent<<<(N_NODES * HD / 8 + 255) / 256, 256, 0, stream>>>(ent_emb, ent_hl);
    k_rw<<<N_REL2, 128, 0, stream>>>(rel_emb, neigh_w, RW, R_hl);
    k_edge_all<<<N_EDGES / 16, 256, 0, stream>>>(ent_hl, R_hl, rel_id, dst, counts, packed);
    k_node_acc<<<N_NODES / 4, 256, 0, stream>>>(RW, row_off, packed, out);
    k_stats<<<N_NODES / 64, 256, 0, stream>>>(out, colsum, colsumsq);
    k_apply<<<N_NODES * HD / 4 / 256, 256, 0, stream>>>(out, colsum, colsumsq, bn_gamma, bn_beta);
}